// Round 4
// baseline (105.657 us; speedup 1.0000x reference)
//
#include <hip/hip_runtime.h>
#include <cstdint>
#include <cstddef>

#define TABLE_SIZE 524288   // 2^19
#define CROP 256
#define TILE 16             // 16x16 px per block, 1 px/thread

// grid resolutions: int(round(16 * 1.5^l)), Python banker's rounding
#define LN_INIT {16, 24, 36, 54, 81, 122, 182, 273, 410, 615, 923, 1384, 2076, 3114, 4671, 7006}
#define SEED(l) ((uint32_t)(15485907386658061715ULL ^ ((uint64_t)(l) * 11400714819323198485ULL)))
#define SEED_INIT {SEED(0),SEED(1),SEED(2),SEED(3),SEED(4),SEED(5),SEED(6),SEED(7), \
                   SEED(8),SEED(9),SEED(10),SEED(11),SEED(12),SEED(13),SEED(14),SEED(15)}

// runtime-indexed copies (pass-A staging uses dynamic level index)
__device__ __constant__ int      c_levelN[16] = LN_INIT;
__device__ __constant__ uint32_t c_seed[16]   = SEED_INIT;

// Per-level corner-rectangle width NX_l = floor(15*scale)+4 and LDS offsets.
// Bound proof: read col index <= floor((bx+15)s)_f32 +1 - floor(bx*s)_f32.
// All integers in range are f32-exact, so the lower floor never rounds below
// its real value; the upper can gain at most +1 -> index <= floor(15s)+3.
// NX: {4,4,4,4,4,4,4,4,5,6,7,9,11,15,21,29}; CNT=NX^2; OFF = prefix sum = 1947 total.

__global__ __launch_bounds__(256)
void HashTableEncoder2D_59339268161685_kernel(const float* __restrict__ tables,
                                              const int* __restrict__ x0,
                                              const int* __restrict__ y0,
                                              float* __restrict__ out)
{
    constexpr int      LN[16]   = LN_INIT;
    constexpr uint32_t SEEDC[16]= SEED_INIT;
    constexpr int      NXA[16]  = {4,4,4,4,4,4,4,4,5,6,7,9,11,15,21,29};
    constexpr int      OFFA[16] = {0,16,32,48,64,80,96,112,128,153,189,238,319,440,665,1106};

    __shared__ float2 lds[1947];   // 15,576 B -> 8 blocks/CU (wave-capped)

    // blockIdx round-robins XCDs: XCD k owns crops {2k, 2k+1} (L2 table locality)
    const int xcd  = blockIdx.x & 7;
    const int s    = blockIdx.x >> 3;        // [0,512)
    const int b    = 2 * xcd + (s >> 8);     // crop id
    const int tile = s & 255;
    const int tx   = (tile & 15) * TILE;
    const int ty   = (tile >> 4) * TILE;
    const int tid  = threadIdx.x;

    // tile-origin pixel center; exact in f32 (k+0.5, k < 2^22)
    const float bx = (float)(x0[b] + tx) + 0.5f;
    const float by = (float)(y0[b] + ty) + 0.5f;

    // ---- stage ALL levels' corner rectangles, then ONE barrier ----

    // levels 0..7: 16 corners each, all 8 levels in one lane-parallel pass
    if (tid < 128) {
        const int l   = tid >> 4;
        const int idx = tid & 15;
        const int row = idx >> 2, col = idx & 3;
        const float sc = (float)c_levelN[l] * (1.0f / 4096.0f);
        const int ixlo = (int)floorf(bx * sc);
        const int iylo = (int)floorf(by * sc);
        const uint32_t h = ((uint32_t)(ixlo + col) * 2654435761u)
                         ^ ((uint32_t)(iylo + row) * 805459861u) ^ c_seed[l];
        lds[16 * l + idx] =
            ((const float2*)tables)[(size_t)l * TABLE_SIZE + (h & (TABLE_SIZE - 1))];
    }

    // levels 8..15: static per-level loops (compile-time NX/CNT/OFF -> magic div)
    #pragma unroll
    for (int l = 8; l < 16; ++l) {
        const int NX  = NXA[l];
        const int CNT = NX * NX;
        const int OFF = OFFA[l];
        const float sc = (float)LN[l] * (1.0f / 4096.0f);
        const int ixlo = (int)floorf(bx * sc);
        const int iylo = (int)floorf(by * sc);
        const uint32_t seed = SEEDC[l];
        const float2* __restrict__ T = (const float2*)tables + (size_t)l * TABLE_SIZE;
        for (int c = tid; c < CNT; c += 256) {
            const int row = c / NX;          // constant divisor
            const int col = c - row * NX;
            const uint32_t h = ((uint32_t)(ixlo + col) * 2654435761u)
                             ^ ((uint32_t)(iylo + row) * 805459861u) ^ seed;
            lds[OFF + c] = T[h & (TABLE_SIZE - 1)];
        }
    }

    __syncthreads();   // the only barrier

    // ---- 16 bilinear levels per thread, no further sync ----
    const int j = tid & 15;
    const int i = tid >> 4;
    const float px = bx + (float)j;   // exact; equals reference pxf
    const float py = by + (float)i;

    float* o0 = out + (size_t)b * (size_t)(32 * CROP * CROP)
                    + (ty + i) * CROP + (tx + j);

    #pragma unroll
    for (int l = 0; l < 16; ++l) {
        const float sc = (float)LN[l] * (1.0f / 4096.0f);
        const int NX  = NXA[l];
        const int OFF = OFFA[l];
        const int ixlo = (int)floorf(bx * sc);   // same ops as staging -> identical
        const int iylo = (int)floorf(by * sc);

        const float gx = px * sc;
        const float gy = py * sc;
        const float fxf = floorf(gx);
        const float fyf = floorf(gy);
        const float fx = gx - fxf;
        const float fy = gy - fyf;

        const int base = OFF + ((int)fyf - iylo) * NX + ((int)fxf - ixlo);
        const float2 f00 = lds[base];
        const float2 f10 = lds[base + 1];
        const float2 f01 = lds[base + NX];
        const float2 f11 = lds[base + NX + 1];

        const float w00 = (1.0f - fx) * (1.0f - fy);
        const float w10 = fx * (1.0f - fy);
        const float w01 = (1.0f - fx) * fy;
        const float w11 = fx * fy;

        const float e0 = w00 * f00.x + w10 * f10.x + w01 * f01.x + w11 * f11.x;
        const float e1 = w00 * f00.y + w10 * f10.y + w01 * f01.y + w11 * f11.y;

        __builtin_nontemporal_store(e0, o0 + (size_t)(2 * l)     * (CROP * CROP));
        __builtin_nontemporal_store(e1, o0 + (size_t)(2 * l + 1) * (CROP * CROP));
    }
}

extern "C" void kernel_launch(void* const* d_in, const int* in_sizes, int n_in,
                              void* d_out, int out_size, void* d_ws, size_t ws_size,
                              hipStream_t stream)
{
    const float* tables = (const float*)d_in[0];
    const int*   x0     = (const int*)d_in[1];
    const int*   y0     = (const int*)d_in[2];
    float* out = (float*)d_out;

    // 16 crops x 256 tiles (16x16 px) = 4096 blocks x 256 threads
    HashTableEncoder2D_59339268161685_kernel<<<4096, 256, 0, stream>>>(tables, x0, y0, out);
}

// Round 6
// 73.646 us; speedup vs baseline: 1.4347x; 1.4347x over previous
//
#include <hip/hip_runtime.h>
#include <cstdint>
#include <cstddef>

#define LEVELS 16
#define TABLE_SIZE 524288   // 2^19
#define CROP 256
#define TILE 32             // 32x32 px per block
#define NXMAX 57            // max corners/axis at l15: floor(31*1.7104)+3 margin

typedef float f32x2 __attribute__((ext_vector_type(2)));   // builtin-compatible

__device__ __constant__ int c_levelN[LEVELS] = {
    16, 24, 36, 54, 81, 122, 182, 273, 410, 615, 923, 1384, 2076, 3114, 4671, 7006
};
__device__ __constant__ uint32_t c_seed[LEVELS] = {
    (uint32_t)(15485907386658061715ULL ^ ( 0ULL * 11400714819323198485ULL)),
    (uint32_t)(15485907386658061715ULL ^ ( 1ULL * 11400714819323198485ULL)),
    (uint32_t)(15485907386658061715ULL ^ ( 2ULL * 11400714819323198485ULL)),
    (uint32_t)(15485907386658061715ULL ^ ( 3ULL * 11400714819323198485ULL)),
    (uint32_t)(15485907386658061715ULL ^ ( 4ULL * 11400714819323198485ULL)),
    (uint32_t)(15485907386658061715ULL ^ ( 5ULL * 11400714819323198485ULL)),
    (uint32_t)(15485907386658061715ULL ^ ( 6ULL * 11400714819323198485ULL)),
    (uint32_t)(15485907386658061715ULL ^ ( 7ULL * 11400714819323198485ULL)),
    (uint32_t)(15485907386658061715ULL ^ ( 8ULL * 11400714819323198485ULL)),
    (uint32_t)(15485907386658061715ULL ^ ( 9ULL * 11400714819323198485ULL)),
    (uint32_t)(15485907386658061715ULL ^ (10ULL * 11400714819323198485ULL)),
    (uint32_t)(15485907386658061715ULL ^ (11ULL * 11400714819323198485ULL)),
    (uint32_t)(15485907386658061715ULL ^ (12ULL * 11400714819323198485ULL)),
    (uint32_t)(15485907386658061715ULL ^ (13ULL * 11400714819323198485ULL)),
    (uint32_t)(15485907386658061715ULL ^ (14ULL * 11400714819323198485ULL)),
    (uint32_t)(15485907386658061715ULL ^ (15ULL * 11400714819323198485ULL)),
};

// R3 structure (level-phased LDS corner dedup, crop->XCD pinning — keeps each
// XCD's live L2 working set ~= one level's lines), upgraded to 512 threads
// (32 waves/CU = 100% occupancy; barriers hidden by 4 co-resident blocks)
// and f32x2 nontemporal stores (exact 131 MB write stream).
__global__ __launch_bounds__(512)
void HashTableEncoder2D_59339268161685_kernel(const float* __restrict__ tables,
                                              const int* __restrict__ x0,
                                              const int* __restrict__ y0,
                                              float* __restrict__ out)
{
    __shared__ float2 lds[NXMAX * NXMAX];   // 25,992 B

    // blockIdx = xcd + 8*s: XCD k owns crops {2k, 2k+1}
    const int xcd  = blockIdx.x & 7;
    const int s    = blockIdx.x >> 3;        // [0,128)
    const int b    = 2 * xcd + (s >> 6);     // crop id
    const int tile = s & 63;                 // 8x8 tiles of 32x32 px
    const int tx = (tile & 7) * TILE;
    const int ty = (tile >> 3) * TILE;
    const int tid = threadIdx.x;

    // tile-origin pixel center; exact in f32
    const float bx = (float)(x0[b] + tx) + 0.5f;
    const float by = (float)(y0[b] + ty) + 0.5f;

    // this thread's 2 pixels: row r, cols jj, jj+1
    const int r  = tid >> 4;          // 0..31
    const int jj = (tid & 15) * 2;    // 0,2,..,30
    const float pyv = by + (float)r;          // exact
    const float px0 = bx + (float)jj;         // exact
    const float px1 = px0 + 1.0f;             // exact

    float* orow = out + (size_t)b * (size_t)(32 * CROP * CROP)
                      + (ty + r) * CROP + (tx + jj);

    for (int l = 0; l < LEVELS; ++l) {
        const float scale = (float)c_levelN[l] * (1.0f / 4096.0f); // exact dyadic
        const uint32_t seed = c_seed[l];

        const int ixlo = (int)floorf(bx * scale);
        const int iylo = (int)floorf(by * scale);
        const int nx = ((int)floorf((bx + 31.0f) * scale) + 1) - ixlo + 1; // <= 56
        const int ny = ((int)floorf((by + 31.0f) * scale) + 1) - iylo + 1;

        __syncthreads();   // previous level's LDS readers done

        const float2* __restrict__ T =
            (const float2*)(tables + (size_t)l * (size_t)(TABLE_SIZE * 2));
        for (int c = tid; c < NXMAX * ny; c += 512) {
            const int row = c / NXMAX;            // const-div -> magic mul
            const int col = c - row * NXMAX;
            if (col < nx) {
                const uint32_t h = ((uint32_t)(ixlo + col) * 2654435761u)
                                 ^ ((uint32_t)(iylo + row) * 805459861u) ^ seed;
                lds[c] = T[h & (TABLE_SIZE - 1)];
            }
        }
        __syncthreads();

        // two pixels, bilinear from LDS (same op sequence as verified rounds)
        const float gy  = pyv * scale;
        const float fyf = floorf(gy);
        const float fy  = gy - fyf;
        const int rowb  = ((int)fyf - iylo) * NXMAX - ixlo;

        const float gx0 = px0 * scale;
        const float fx0f = floorf(gx0);
        const float fx0 = gx0 - fx0f;
        const int base0 = rowb + (int)fx0f;

        const float gx1 = px1 * scale;
        const float fx1f = floorf(gx1);
        const float fx1 = gx1 - fx1f;
        const int base1 = rowb + (int)fx1f;

        const float2 a00 = lds[base0];
        const float2 a10 = lds[base0 + 1];
        const float2 a01 = lds[base0 + NXMAX];
        const float2 a11 = lds[base0 + NXMAX + 1];
        const float2 b00 = lds[base1];
        const float2 b10 = lds[base1 + 1];
        const float2 b01 = lds[base1 + NXMAX];
        const float2 b11 = lds[base1 + NXMAX + 1];

        const float ua00 = (1.0f - fx0) * (1.0f - fy);
        const float ua10 = fx0 * (1.0f - fy);
        const float ua01 = (1.0f - fx0) * fy;
        const float ua11 = fx0 * fy;
        const float ub00 = (1.0f - fx1) * (1.0f - fy);
        const float ub10 = fx1 * (1.0f - fy);
        const float ub01 = (1.0f - fx1) * fy;
        const float ub11 = fx1 * fy;

        f32x2 c0, c1;
        c0.x = ua00 * a00.x + ua10 * a10.x + ua01 * a01.x + ua11 * a11.x;
        c1.x = ua00 * a00.y + ua10 * a10.y + ua01 * a01.y + ua11 * a11.y;
        c0.y = ub00 * b00.x + ub10 * b10.x + ub01 * b01.x + ub11 * b11.x;
        c1.y = ub00 * b00.y + ub10 * b10.y + ub01 * b01.y + ub11 * b11.y;

        __builtin_nontemporal_store(c0, (f32x2*)(orow + (size_t)(2 * l) * (CROP * CROP)));
        __builtin_nontemporal_store(c1, (f32x2*)(orow + (size_t)(2 * l + 1) * (CROP * CROP)));
    }
}

extern "C" void kernel_launch(void* const* d_in, const int* in_sizes, int n_in,
                              void* d_out, int out_size, void* d_ws, size_t ws_size,
                              hipStream_t stream)
{
    const float* tables = (const float*)d_in[0];
    const int*   x0     = (const int*)d_in[1];
    const int*   y0     = (const int*)d_in[2];
    float* out = (float*)d_out;

    // 16 crops x 64 tiles = 1024 blocks x 512 threads (4 blocks/CU, 32 waves/CU)
    HashTableEncoder2D_59339268161685_kernel<<<1024, 512, 0, stream>>>(tables, x0, y0, out);
}